// Round 1
// baseline (687.252 us; speedup 1.0000x reference)
//
#include <hip/hip_runtime.h>

// Problem constants (match the JAX reference).
constexpr int NSEG = 10000;
constexpr int BB   = 4;
constexpr int SS   = 200000;
constexpr int DD   = 64;

// out[b, seg[i], d] += v[b, i, d]
// One thread per float4 of v (4 consecutive d). Grid-stride.
__global__ void FDUnsortedSegmentSum_scatter(const float4* __restrict__ v4,
                                             const int*    __restrict__ seg,
                                             float*        __restrict__ out) {
    const int total  = BB * SS * (DD / 4);          // 12,800,000
    const int stride = gridDim.x * blockDim.x;
    for (int idx = blockIdx.x * blockDim.x + threadIdx.x; idx < total; idx += stride) {
        const int d4 = idx & 15;        // which float4 within the D=64 row
        const int t  = idx >> 4;        // b*S + i
        const int i  = t % SS;
        const int b  = t / SS;
        const int sg = seg[i];

        const float4 val = v4[idx];     // coalesced 16B/lane
        float* o = out + ((size_t)b * NSEG + sg) * DD + d4 * 4;
        atomicAdd(o + 0, val.x);
        atomicAdd(o + 1, val.y);
        atomicAdd(o + 2, val.z);
        atomicAdd(o + 3, val.w);
    }
}

extern "C" void kernel_launch(void* const* d_in, const int* in_sizes, int n_in,
                              void* d_out, int out_size, void* d_ws, size_t ws_size,
                              hipStream_t stream) {
    // Inputs (setup_inputs order): data (unused), v, segment_index.
    const float4* v4  = (const float4*)d_in[1];
    const int*    seg = (const int*)d_in[2];
    float*        out = (float*)d_out;

    // Harness poisons d_out with 0xAA and does not re-zero between replays.
    hipMemsetAsync(out, 0, (size_t)out_size * sizeof(float), stream);

    const int total   = BB * SS * (DD / 4);
    const int threads = 256;
    const int blocks  = 4096;           // grid-stride, ~12.8M / 1M threads ≈ 13 iters
    FDUnsortedSegmentSum_scatter<<<blocks, threads, 0, stream>>>(v4, seg, out);
    (void)total; (void)d_ws; (void)ws_size; (void)in_sizes; (void)n_in;
}

// Round 2
// 84.205 us; speedup vs baseline: 8.1617x; 8.1617x over previous
//
#include <hip/hip_runtime.h>

// Problem constants (match the JAX reference).
constexpr int NSEG = 10000;
constexpr int BB   = 4;
constexpr int SS   = 200000;
constexpr int DD   = 64;        // 16 float4 per row

// ---------------------------------------------------------------------------
// Phase 1: histogram of segment ids
__global__ void hist_kernel(const int* __restrict__ seg, int* __restrict__ counts) {
    int i = blockIdx.x * blockDim.x + threadIdx.x;
    if (i < SS) atomicAdd(&counts[seg[i]], 1);
}

// Phase 2: exclusive prefix sum over NSEG counts (single block, 1024 threads)
__global__ void scan_kernel(const int* __restrict__ counts, int* __restrict__ offsets) {
    __shared__ int partial[1024];
    const int tid = threadIdx.x;
    const int PER = (NSEG + 1023) / 1024;     // 10
    const int base = tid * PER;
    int s = 0;
    for (int k = 0; k < PER; ++k) {
        int idx = base + k;
        if (idx < NSEG) s += counts[idx];
    }
    partial[tid] = s;
    __syncthreads();
    // Hillis-Steele inclusive scan over 1024 partials
    for (int off = 1; off < 1024; off <<= 1) {
        int val = (tid >= off) ? partial[tid - off] : 0;
        __syncthreads();
        partial[tid] += val;
        __syncthreads();
    }
    int excl = (tid == 0) ? 0 : partial[tid - 1];
    for (int k = 0; k < PER; ++k) {
        int idx = base + k;
        if (idx < NSEG) {
            offsets[idx] = excl;
            excl += counts[idx];
        }
    }
}

// Phase 3: scatter row indices into segment-sorted order
__global__ void scatter_kernel(const int* __restrict__ seg,
                               const int* __restrict__ offsets,
                               int* __restrict__ cursor,
                               int* __restrict__ sorted_idx) {
    int i = blockIdx.x * blockDim.x + threadIdx.x;
    if (i < SS) {
        int s = seg[i];
        int pos = offsets[s] + atomicAdd(&cursor[s], 1);
        sorted_idx[pos] = i;
    }
}

// Phase 4: gather-sum. Thread owns (b, s, d4); 16-lane group shares a row list.
__global__ void gather_kernel(const float4* __restrict__ v4,
                              const int* __restrict__ offsets,
                              const int* __restrict__ counts,
                              const int* __restrict__ sorted_idx,
                              float4* __restrict__ out4) {
    const int total = BB * NSEG * (DD / 4);   // 640,000
    int idx = blockIdx.x * blockDim.x + threadIdx.x;
    if (idx >= total) return;
    const int d4 = idx & 15;
    const int t  = idx >> 4;                  // b*NSEG + s
    const int s  = t % NSEG;
    const int b  = t / NSEG;

    const int off = offsets[s];
    const int cnt = counts[s];
    const float4* vb = v4 + (size_t)b * SS * (DD / 4);

    float4 acc = make_float4(0.f, 0.f, 0.f, 0.f);
    int j = 0;
    for (; j + 3 < cnt; j += 4) {             // 4 independent row loads in flight
        int i0 = sorted_idx[off + j + 0];
        int i1 = sorted_idx[off + j + 1];
        int i2 = sorted_idx[off + j + 2];
        int i3 = sorted_idx[off + j + 3];
        float4 a0 = vb[(size_t)i0 * 16 + d4];
        float4 a1 = vb[(size_t)i1 * 16 + d4];
        float4 a2 = vb[(size_t)i2 * 16 + d4];
        float4 a3 = vb[(size_t)i3 * 16 + d4];
        acc.x += (a0.x + a1.x) + (a2.x + a3.x);
        acc.y += (a0.y + a1.y) + (a2.y + a3.y);
        acc.z += (a0.z + a1.z) + (a2.z + a3.z);
        acc.w += (a0.w + a1.w) + (a2.w + a3.w);
    }
    for (; j < cnt; ++j) {
        int i0 = sorted_idx[off + j];
        float4 a0 = vb[(size_t)i0 * 16 + d4];
        acc.x += a0.x; acc.y += a0.y; acc.z += a0.z; acc.w += a0.w;
    }
    out4[(size_t)t * 16 + d4] = acc;          // every output element written once
}

// Fallback (round-1 kernel) in case ws_size is too small.
__global__ void scatter_atomic_kernel(const float4* __restrict__ v4,
                                      const int* __restrict__ seg,
                                      float* __restrict__ out) {
    const int total  = BB * SS * (DD / 4);
    const int stride = gridDim.x * blockDim.x;
    for (int idx = blockIdx.x * blockDim.x + threadIdx.x; idx < total; idx += stride) {
        const int d4 = idx & 15;
        const int t  = idx >> 4;
        const int i  = t % SS;
        const int b  = t / SS;
        const int sg = seg[i];
        const float4 val = v4[idx];
        float* o = out + ((size_t)b * NSEG + sg) * DD + d4 * 4;
        atomicAdd(o + 0, val.x);
        atomicAdd(o + 1, val.y);
        atomicAdd(o + 2, val.z);
        atomicAdd(o + 3, val.w);
    }
}

extern "C" void kernel_launch(void* const* d_in, const int* in_sizes, int n_in,
                              void* d_out, int out_size, void* d_ws, size_t ws_size,
                              hipStream_t stream) {
    const float4* v4  = (const float4*)d_in[1];
    const int*    seg = (const int*)d_in[2];

    // Workspace layout: counts[NSEG] | offsets[NSEG] | cursor[NSEG] | sorted_idx[SS]
    const size_t need = (size_t)(3 * NSEG + SS) * sizeof(int);
    if (ws_size < need) {
        // Fallback: atomic scatter (round-1 path)
        float* out = (float*)d_out;
        hipMemsetAsync(out, 0, (size_t)out_size * sizeof(float), stream);
        scatter_atomic_kernel<<<4096, 256, 0, stream>>>(v4, seg, out);
        return;
    }

    int* counts     = (int*)d_ws;
    int* offsets    = counts + NSEG;
    int* cursor     = offsets + NSEG;
    int* sorted_idx = cursor + NSEG;

    // counts and cursor must start at zero every call (graph replays).
    hipMemsetAsync(counts, 0, (size_t)NSEG * sizeof(int), stream);
    hipMemsetAsync(cursor, 0, (size_t)NSEG * sizeof(int), stream);

    hist_kernel<<<(SS + 255) / 256, 256, 0, stream>>>(seg, counts);
    scan_kernel<<<1, 1024, 0, stream>>>(counts, offsets);
    scatter_kernel<<<(SS + 255) / 256, 256, 0, stream>>>(seg, offsets, cursor, sorted_idx);

    const int total = BB * NSEG * (DD / 4);   // 640,000
    gather_kernel<<<(total + 255) / 256, 256, 0, stream>>>(
        v4, offsets, counts, sorted_idx, (float4*)d_out);

    (void)in_sizes; (void)n_in; (void)out_size;
}

// Round 3
// 84.114 us; speedup vs baseline: 8.1705x; 1.0011x over previous
//
#include <hip/hip_runtime.h>

// Problem constants (match the JAX reference).
constexpr int NSEG = 10000;
constexpr int BB   = 4;
constexpr int SS   = 200000;    // divisible by 4
constexpr int DD   = 64;        // 16 float4 per row

// ---------------------------------------------------------------------------
// Phase 1: histogram of segment ids (int4-vectorized reads)
__global__ void hist_kernel(const int4* __restrict__ seg4, int* __restrict__ counts) {
    int i = blockIdx.x * blockDim.x + threadIdx.x;
    if (i < SS / 4) {
        int4 s = seg4[i];
        atomicAdd(&counts[s.x], 1);
        atomicAdd(&counts[s.y], 1);
        atomicAdd(&counts[s.z], 1);
        atomicAdd(&counts[s.w], 1);
    }
}

// Phase 2: exclusive prefix sum over NSEG counts (single block, 1024 threads)
__global__ void scan_kernel(const int* __restrict__ counts, int* __restrict__ offsets) {
    __shared__ int partial[1024];
    const int tid = threadIdx.x;
    const int PER = (NSEG + 1023) / 1024;     // 10
    const int base = tid * PER;
    int s = 0;
    for (int k = 0; k < PER; ++k) {
        int idx = base + k;
        if (idx < NSEG) s += counts[idx];
    }
    partial[tid] = s;
    __syncthreads();
    for (int off = 1; off < 1024; off <<= 1) {
        int val = (tid >= off) ? partial[tid - off] : 0;
        __syncthreads();
        partial[tid] += val;
        __syncthreads();
    }
    int excl = (tid == 0) ? 0 : partial[tid - 1];
    for (int k = 0; k < PER; ++k) {
        int idx = base + k;
        if (idx < NSEG) {
            offsets[idx] = excl;
            excl += counts[idx];
        }
    }
}

// Phase 3: scatter row indices into segment-sorted order.
// atomicAdd on offsets itself: afterwards offsets[s] == inclusive scan.
__global__ void scatter_kernel(const int4* __restrict__ seg4,
                               int* __restrict__ offsets,
                               int* __restrict__ sorted_idx) {
    int i = blockIdx.x * blockDim.x + threadIdx.x;
    if (i < SS / 4) {
        int4 sg = seg4[i];
        int base = i * 4;
        sorted_idx[atomicAdd(&offsets[sg.x], 1)] = base + 0;
        sorted_idx[atomicAdd(&offsets[sg.y], 1)] = base + 1;
        sorted_idx[atomicAdd(&offsets[sg.z], 1)] = base + 2;
        sorted_idx[atomicAdd(&offsets[sg.w], 1)] = base + 3;
    }
}

// Phase 4: gather-sum, all 4 batches fused per thread.
// Thread owns (s, d4); 16-lane group shares the segment's row list.
__global__ void __launch_bounds__(256)
gather_kernel(const float4* __restrict__ v4,
              const int* __restrict__ offs_incl,   // inclusive scan (post-scatter)
              const int* __restrict__ counts,
              const int* __restrict__ sorted_idx,
              float4* __restrict__ out4) {
    int idx = blockIdx.x * blockDim.x + threadIdx.x;   // [0, NSEG*16)
    const int d4 = idx & 15;
    const int s  = idx >> 4;
    if (s >= NSEG) return;

    const int cnt = counts[s];
    const int off = offs_incl[s] - cnt;

    float4 acc[BB];
    #pragma unroll
    for (int b = 0; b < BB; ++b) acc[b] = make_float4(0.f, 0.f, 0.f, 0.f);

    int j = 0;
    for (; j + 1 < cnt; j += 2) {             // 2 rows x 4 batches = 8 loads in flight
        const int i0 = sorted_idx[off + j];
        const int i1 = sorted_idx[off + j + 1];
        #pragma unroll
        for (int b = 0; b < BB; ++b) {
            float4 a0 = v4[((size_t)b * SS + i0) * 16 + d4];
            float4 a1 = v4[((size_t)b * SS + i1) * 16 + d4];
            acc[b].x += a0.x + a1.x;
            acc[b].y += a0.y + a1.y;
            acc[b].z += a0.z + a1.z;
            acc[b].w += a0.w + a1.w;
        }
    }
    if (j < cnt) {
        const int i0 = sorted_idx[off + j];
        #pragma unroll
        for (int b = 0; b < BB; ++b) {
            float4 a0 = v4[((size_t)b * SS + i0) * 16 + d4];
            acc[b].x += a0.x; acc[b].y += a0.y;
            acc[b].z += a0.z; acc[b].w += a0.w;
        }
    }

    #pragma unroll
    for (int b = 0; b < BB; ++b)
        out4[((size_t)b * NSEG + s) * 16 + d4] = acc[b];   // written exactly once
}

// Fallback (round-1 kernel) in case ws_size is too small.
__global__ void scatter_atomic_kernel(const float4* __restrict__ v4,
                                      const int* __restrict__ seg,
                                      float* __restrict__ out) {
    const int total  = BB * SS * (DD / 4);
    const int stride = gridDim.x * blockDim.x;
    for (int idx = blockIdx.x * blockDim.x + threadIdx.x; idx < total; idx += stride) {
        const int d4 = idx & 15;
        const int t  = idx >> 4;
        const int i  = t % SS;
        const int b  = t / SS;
        const int sg = seg[i];
        const float4 val = v4[idx];
        float* o = out + ((size_t)b * NSEG + sg) * DD + d4 * 4;
        atomicAdd(o + 0, val.x);
        atomicAdd(o + 1, val.y);
        atomicAdd(o + 2, val.z);
        atomicAdd(o + 3, val.w);
    }
}

extern "C" void kernel_launch(void* const* d_in, const int* in_sizes, int n_in,
                              void* d_out, int out_size, void* d_ws, size_t ws_size,
                              hipStream_t stream) {
    const float4* v4  = (const float4*)d_in[1];
    const int*    seg = (const int*)d_in[2];

    // Workspace layout: counts[NSEG] | offsets[NSEG] | sorted_idx[SS]
    const size_t need = (size_t)(2 * NSEG + SS) * sizeof(int);
    if (ws_size < need) {
        float* out = (float*)d_out;
        hipMemsetAsync(out, 0, (size_t)out_size * sizeof(float), stream);
        scatter_atomic_kernel<<<4096, 256, 0, stream>>>(v4, seg, out);
        return;
    }

    int* counts     = (int*)d_ws;
    int* offsets    = counts + NSEG;
    int* sorted_idx = offsets + NSEG;

    // counts must start at zero every call (graph replays).
    hipMemsetAsync(counts, 0, (size_t)NSEG * sizeof(int), stream);

    hist_kernel<<<(SS / 4 + 255) / 256, 256, 0, stream>>>((const int4*)seg, counts);
    scan_kernel<<<1, 1024, 0, stream>>>(counts, offsets);
    scatter_kernel<<<(SS / 4 + 255) / 256, 256, 0, stream>>>((const int4*)seg, offsets, sorted_idx);

    const int total = NSEG * (DD / 4);        // 160,000 threads
    gather_kernel<<<(total + 255) / 256, 256, 0, stream>>>(
        v4, offsets, counts, sorted_idx, (float4*)d_out);

    (void)in_sizes; (void)n_in; (void)out_size;
}

// Round 5
// 66.805 us; speedup vs baseline: 10.2875x; 1.2591x over previous
//
#include <hip/hip_runtime.h>

// Problem constants (match the JAX reference).
constexpr int NSEG = 10000;
constexpr int BB   = 4;
constexpr int SS   = 200000;    // divisible by 4
constexpr int DD   = 64;        // 16 float4 per row

constexpr int CAP     = 48;     // bucket capacity per segment (mean 20, P(>48) ~ 1e-8)
constexpr int OVF_CAP = 4096;   // overflow list capacity (unused in practice)

// ---------------------------------------------------------------------------
// Phase 1 (single pass): histogram + bucket scatter, int4-vectorized.
__global__ void bucket_kernel(const int4* __restrict__ seg4,
                              int* __restrict__ cnt,
                              int* __restrict__ ovf_cnt,
                              int* __restrict__ bucket,
                              int* __restrict__ ovf) {
    int i = blockIdx.x * blockDim.x + threadIdx.x;
    if (i >= SS / 4) return;
    int4 sg = seg4[i];
    int base = i * 4;
    int ss[4] = {sg.x, sg.y, sg.z, sg.w};
    #pragma unroll
    for (int k = 0; k < 4; ++k) {
        int s = ss[k];
        int p = atomicAdd(&cnt[s], 1);
        if (p < CAP) {
            bucket[s * CAP + p] = base + k;
        } else {
            int o = atomicAdd(ovf_cnt, 1);
            if (o < OVF_CAP) ovf[o] = base + k;
        }
    }
}

// Phase 2: gather-sum. Thread owns (s, d4); 16-lane group shares a bucket.
__global__ void __launch_bounds__(256)
gather_kernel(const float4* __restrict__ v4,
              const int* __restrict__ cnt,
              const int* __restrict__ bucket,
              float4* __restrict__ out4) {
    int idx = blockIdx.x * blockDim.x + threadIdx.x;   // [0, NSEG*16)
    const int d4 = idx & 15;
    const int s  = idx >> 4;
    if (s >= NSEG) return;

    int n = cnt[s];
    if (n > CAP) n = CAP;
    const int* bk = bucket + s * CAP;    // byte offset s*192: 16B-aligned

    float4 acc[BB];
    #pragma unroll
    for (int b = 0; b < BB; ++b) acc[b] = make_float4(0.f, 0.f, 0.f, 0.f);

    int j = 0;
    for (; j + 3 < n; j += 4) {          // 4 rows x 4 batches = 16 loads in flight
        int4 r = *(const int4*)(bk + j);
        #pragma unroll
        for (int b = 0; b < BB; ++b) {
            const float4* vb = v4 + (size_t)b * SS * 16;
            float4 a0 = vb[(size_t)r.x * 16 + d4];
            float4 a1 = vb[(size_t)r.y * 16 + d4];
            float4 a2 = vb[(size_t)r.z * 16 + d4];
            float4 a3 = vb[(size_t)r.w * 16 + d4];
            acc[b].x += (a0.x + a1.x) + (a2.x + a3.x);
            acc[b].y += (a0.y + a1.y) + (a2.y + a3.y);
            acc[b].z += (a0.z + a1.z) + (a2.z + a3.z);
            acc[b].w += (a0.w + a1.w) + (a2.w + a3.w);
        }
    }
    for (; j < n; ++j) {
        int r0 = bk[j];
        #pragma unroll
        for (int b = 0; b < BB; ++b) {
            float4 a0 = v4[((size_t)b * SS + r0) * 16 + d4];
            acc[b].x += a0.x; acc[b].y += a0.y;
            acc[b].z += a0.z; acc[b].w += a0.w;
        }
    }
    #pragma unroll
    for (int b = 0; b < BB; ++b)
        out4[((size_t)b * NSEG + s) * 16 + d4] = acc[b];   // written exactly once
}

// Phase 3: overflow fixup (atomicAdd the rare rows beyond CAP). Empty in practice.
__global__ void fixup_kernel(const float4* __restrict__ v4,
                             const int* __restrict__ seg,
                             const int* __restrict__ ovf_cnt,
                             const int* __restrict__ ovf,
                             float* __restrict__ out) {
    int n = *ovf_cnt;
    if (n > OVF_CAP) n = OVF_CAP;
    for (int idx = blockIdx.x * blockDim.x + threadIdx.x; idx < n * 16;
         idx += gridDim.x * blockDim.x) {
        int r  = ovf[idx >> 4];
        int d4 = idx & 15;
        int s  = seg[r];
        #pragma unroll
        for (int b = 0; b < BB; ++b) {
            float4 a = v4[((size_t)b * SS + r) * 16 + d4];
            float* o = out + ((size_t)b * NSEG + s) * DD + d4 * 4;
            atomicAdd(o + 0, a.x);
            atomicAdd(o + 1, a.y);
            atomicAdd(o + 2, a.z);
            atomicAdd(o + 3, a.w);
        }
    }
}

// Fallback (round-1 kernel) in case ws_size is too small.
__global__ void scatter_atomic_kernel(const float4* __restrict__ v4,
                                      const int* __restrict__ seg,
                                      float* __restrict__ out) {
    const int total  = BB * SS * (DD / 4);
    const int stride = gridDim.x * blockDim.x;
    for (int idx = blockIdx.x * blockDim.x + threadIdx.x; idx < total; idx += stride) {
        const int d4 = idx & 15;
        const int t  = idx >> 4;
        const int i  = t % SS;
        const int b  = t / SS;
        const int sg = seg[i];
        const float4 val = v4[idx];
        float* o = out + ((size_t)b * NSEG + sg) * DD + d4 * 4;
        atomicAdd(o + 0, val.x);
        atomicAdd(o + 1, val.y);
        atomicAdd(o + 2, val.z);
        atomicAdd(o + 3, val.w);
    }
}

extern "C" void kernel_launch(void* const* d_in, const int* in_sizes, int n_in,
                              void* d_out, int out_size, void* d_ws, size_t ws_size,
                              hipStream_t stream) {
    const float4* v4  = (const float4*)d_in[1];
    const int*    seg = (const int*)d_in[2];

    // Workspace: cnt[NSEG] | ovf_cnt[1] | bucket[NSEG*CAP] | ovf[OVF_CAP]
    const size_t need = (size_t)(NSEG + 1 + NSEG * CAP + OVF_CAP) * sizeof(int);
    if (ws_size < need) {
        float* out = (float*)d_out;
        hipMemsetAsync(out, 0, (size_t)out_size * sizeof(float), stream);
        scatter_atomic_kernel<<<4096, 256, 0, stream>>>(v4, seg, out);
        return;
    }

    int* cnt     = (int*)d_ws;
    int* ovf_cnt = cnt + NSEG;
    int* bucket  = ovf_cnt + 1;
    int* ovf     = bucket + NSEG * CAP;

    // cnt + ovf_cnt must be zero every call (graph replays).
    hipMemsetAsync(cnt, 0, (size_t)(NSEG + 1) * sizeof(int), stream);

    bucket_kernel<<<(SS / 4 + 255) / 256, 256, 0, stream>>>(
        (const int4*)seg, cnt, ovf_cnt, bucket, ovf);

    const int total = NSEG * (DD / 4);        // 160,000 threads
    gather_kernel<<<(total + 255) / 256, 256, 0, stream>>>(
        v4, cnt, bucket, (float4*)d_out);

    fixup_kernel<<<4, 256, 0, stream>>>(v4, seg, ovf_cnt, ovf, (float*)d_out);

    (void)in_sizes; (void)n_in; (void)out_size;
}

// Round 6
// 59.896 us; speedup vs baseline: 11.4741x; 1.1153x over previous
//
#include <hip/hip_runtime.h>

// Problem constants (match the JAX reference).
constexpr int NSEG = 10000;
constexpr int BB   = 4;
constexpr int SS   = 200000;    // divisible by 4
constexpr int DD   = 64;        // 16 float4 per row

constexpr int CAP     = 48;     // bucket capacity per segment (mean 20, P(>48) ~ 1e-8)
constexpr int OVF_CAP = 4096;   // overflow list capacity (empty in practice)

// ---------------------------------------------------------------------------
// Phase 1 (single pass): histogram + bucket scatter, int4-vectorized.
__global__ void bucket_kernel(const int4* __restrict__ seg4,
                              int* __restrict__ cnt,
                              int* __restrict__ ovf_cnt,
                              int* __restrict__ bucket,
                              int* __restrict__ ovf) {
    int i = blockIdx.x * blockDim.x + threadIdx.x;
    if (i >= SS / 4) return;
    int4 sg = seg4[i];
    int base = i * 4;
    int ss[4] = {sg.x, sg.y, sg.z, sg.w};
    #pragma unroll
    for (int k = 0; k < 4; ++k) {
        int s = ss[k];
        int p = atomicAdd(&cnt[s], 1);
        if (p < CAP) {
            bucket[s * CAP + p] = base + k;
        } else {
            int o = atomicAdd(ovf_cnt, 1);
            if (o < OVF_CAP) ovf[o] = base + k;
        }
    }
}

// Phase 2: gather-sum. One 64-lane wave per segment; lane = (d4, b).
// Each lane owns batch b's float4 column d4 and loops over all rows of the
// segment (8-row unroll -> 8 outstanding 16B loads per lane, 32 x 256B
// chunks per wave). No cross-lane reduction needed; one store per lane.
// Overflow fixup folded in (ovf list is empty in practice).
__global__ void __launch_bounds__(256)
gather_kernel(const float4* __restrict__ v4,
              const int* __restrict__ cnt,
              const int* __restrict__ bucket,
              const int* __restrict__ seg,
              const int* __restrict__ ovf_cnt,
              const int* __restrict__ ovf,
              float4* __restrict__ out4) {
    const int idx  = blockIdx.x * blockDim.x + threadIdx.x;   // [0, NSEG*64)
    const int lane = threadIdx.x & 63;
    const int d4   = lane & 15;
    const int b    = lane >> 4;
    const int s    = idx >> 6;
    if (s >= NSEG) return;

    int n = cnt[s];
    if (n > CAP) n = CAP;
    const int* bk = bucket + s * CAP;                 // 192B-aligned
    const float4* vb = v4 + (size_t)b * SS * 16;

    float4 acc = make_float4(0.f, 0.f, 0.f, 0.f);

    int j = 0;
    for (; j + 7 < n; j += 8) {                       // 8 rows in flight per lane
        int4 r0 = *(const int4*)(bk + j);
        int4 r1 = *(const int4*)(bk + j + 4);
        float4 a0 = vb[(size_t)r0.x * 16 + d4];
        float4 a1 = vb[(size_t)r0.y * 16 + d4];
        float4 a2 = vb[(size_t)r0.z * 16 + d4];
        float4 a3 = vb[(size_t)r0.w * 16 + d4];
        float4 a4 = vb[(size_t)r1.x * 16 + d4];
        float4 a5 = vb[(size_t)r1.y * 16 + d4];
        float4 a6 = vb[(size_t)r1.z * 16 + d4];
        float4 a7 = vb[(size_t)r1.w * 16 + d4];
        acc.x += ((a0.x + a1.x) + (a2.x + a3.x)) + ((a4.x + a5.x) + (a6.x + a7.x));
        acc.y += ((a0.y + a1.y) + (a2.y + a3.y)) + ((a4.y + a5.y) + (a6.y + a7.y));
        acc.z += ((a0.z + a1.z) + (a2.z + a3.z)) + ((a4.z + a5.z) + (a6.z + a7.z));
        acc.w += ((a0.w + a1.w) + (a2.w + a3.w)) + ((a4.w + a5.w) + (a6.w + a7.w));
    }
    for (; j + 3 < n; j += 4) {
        int4 r0 = *(const int4*)(bk + j);
        float4 a0 = vb[(size_t)r0.x * 16 + d4];
        float4 a1 = vb[(size_t)r0.y * 16 + d4];
        float4 a2 = vb[(size_t)r0.z * 16 + d4];
        float4 a3 = vb[(size_t)r0.w * 16 + d4];
        acc.x += (a0.x + a1.x) + (a2.x + a3.x);
        acc.y += (a0.y + a1.y) + (a2.y + a3.y);
        acc.z += (a0.z + a1.z) + (a2.z + a3.z);
        acc.w += (a0.w + a1.w) + (a2.w + a3.w);
    }
    for (; j < n; ++j) {
        int r0 = bk[j];
        float4 a0 = vb[(size_t)r0 * 16 + d4];
        acc.x += a0.x; acc.y += a0.y; acc.z += a0.z; acc.w += a0.w;
    }

    // Overflow fixup (rows beyond CAP) — empty in practice, one cached load.
    int no = *ovf_cnt;
    if (no > 0) {
        if (no > OVF_CAP) no = OVF_CAP;
        for (int t = 0; t < no; ++t) {
            int r = ovf[t];
            if (seg[r] == s) {
                float4 a0 = vb[(size_t)r * 16 + d4];
                acc.x += a0.x; acc.y += a0.y; acc.z += a0.z; acc.w += a0.w;
            }
        }
    }

    out4[((size_t)b * NSEG + s) * 16 + d4] = acc;     // written exactly once
}

// Fallback (round-1 kernel) in case ws_size is too small.
__global__ void scatter_atomic_kernel(const float4* __restrict__ v4,
                                      const int* __restrict__ seg,
                                      float* __restrict__ out) {
    const int total  = BB * SS * (DD / 4);
    const int stride = gridDim.x * blockDim.x;
    for (int idx = blockIdx.x * blockDim.x + threadIdx.x; idx < total; idx += stride) {
        const int d4 = idx & 15;
        const int t  = idx >> 4;
        const int i  = t % SS;
        const int b  = t / SS;
        const int sg = seg[i];
        const float4 val = v4[idx];
        float* o = out + ((size_t)b * NSEG + sg) * DD + d4 * 4;
        atomicAdd(o + 0, val.x);
        atomicAdd(o + 1, val.y);
        atomicAdd(o + 2, val.z);
        atomicAdd(o + 3, val.w);
    }
}

extern "C" void kernel_launch(void* const* d_in, const int* in_sizes, int n_in,
                              void* d_out, int out_size, void* d_ws, size_t ws_size,
                              hipStream_t stream) {
    const float4* v4  = (const float4*)d_in[1];
    const int*    seg = (const int*)d_in[2];

    // Workspace: cnt[NSEG] | ovf_cnt[1] | bucket[NSEG*CAP] | ovf[OVF_CAP]
    const size_t need = (size_t)(NSEG + 1 + NSEG * CAP + OVF_CAP) * sizeof(int);
    if (ws_size < need) {
        float* out = (float*)d_out;
        hipMemsetAsync(out, 0, (size_t)out_size * sizeof(float), stream);
        scatter_atomic_kernel<<<4096, 256, 0, stream>>>(v4, seg, out);
        return;
    }

    int* cnt     = (int*)d_ws;
    int* ovf_cnt = cnt + NSEG;
    int* bucket  = ovf_cnt + 1;
    int* ovf     = bucket + NSEG * CAP;

    // cnt + ovf_cnt must be zero every call (graph replays).
    hipMemsetAsync(cnt, 0, (size_t)(NSEG + 1) * sizeof(int), stream);

    bucket_kernel<<<(SS / 4 + 255) / 256, 256, 0, stream>>>(
        (const int4*)seg, cnt, ovf_cnt, bucket, ovf);

    const int total = NSEG * 64;              // 640,000 threads, wave per segment
    gather_kernel<<<(total + 255) / 256, 256, 0, stream>>>(
        v4, cnt, bucket, seg, ovf_cnt, ovf, (float4*)d_out);

    (void)in_sizes; (void)n_in; (void)out_size;
}